// Round 1
// baseline (725.923 us; speedup 1.0000x reference)
//
#include <hip/hip_runtime.h>
#include <cstdint>
#include <cstddef>

#define TM 64       // elements (splats) per block
#define BLOCK 256

// MLP dims (fixed by the reference)
//   D_IN = 64 = emb(16) + feats(32) + sh(16), W = 128, out = 3
// X^T in LDS carries only feats+sh (48 rows); emb part is folded into cbias.

__global__ __launch_bounds__(256) void vdc_mlp_kernel(
    const float* __restrict__ feats,      // [N,32]
    const float* __restrict__ dirs,       // [C,N,3]
    const float* __restrict__ emb_tab,    // [1000,16]
    const float* __restrict__ W0,         // [64,128] rows: 0..15 emb, 16..47 feats, 48..63 sh
    const float* __restrict__ b0,         // [128]
    const float* __restrict__ W1,         // [128,128]
    const float* __restrict__ b1,         // [128]
    const float* __restrict__ W2,         // [128,3]
    const float* __restrict__ b2,         // [3]
    const int* __restrict__ embed_ids,    // [C]
    const int* __restrict__ sh_deg_p,     // [1]
    float* __restrict__ out,              // [C,N,3]
    int N)
{
    __shared__ float XT[48 * 64];     // X transposed: XT[k][e], k-major, row stride 64
    __shared__ float HT[128 * 64];    // H0 then H1 transposed: HT[k][e]
    __shared__ float sCB[128];        // b0 + emb @ W0[0:16,:]
    __shared__ float sB1[128];
    __shared__ float sW2[128 * 4];    // W2 padded to stride 4
    __shared__ float sB2[3];

    const int tid = threadIdx.x;
    const int c   = blockIdx.y;
    const int n0  = blockIdx.x * TM;

    // ---------------- phase 0: stage X^T, cbias, small weights ----------------
    {
        // feats -> XT rows 0..31  (thread: e = tid>>2, quarter q = tid&3 -> 8 feats)
        int e = tid >> 2;
        int q = tid & 3;
        int n = n0 + e; if (n >= N) n = N - 1;
        const float4* fp = (const float4*)(feats + (size_t)n * 32);
        float4 fa = fp[q * 2 + 0];
        float4 fb = fp[q * 2 + 1];
        int kb = q * 8;
        XT[(kb + 0) * 64 + e] = fa.x;
        XT[(kb + 1) * 64 + e] = fa.y;
        XT[(kb + 2) * 64 + e] = fa.z;
        XT[(kb + 3) * 64 + e] = fa.w;
        XT[(kb + 4) * 64 + e] = fb.x;
        XT[(kb + 5) * 64 + e] = fb.y;
        XT[(kb + 6) * 64 + e] = fb.z;
        XT[(kb + 7) * 64 + e] = fb.w;
    }
    if (tid < 64) {
        // SH basis -> XT rows 32..47
        int e = tid;
        int n = n0 + e; if (n >= N) n = N - 1;
        const float* dp = dirs + ((size_t)c * N + n) * 3;
        float dx = dp[0], dy = dp[1], dz = dp[2];
        float nrm = sqrtf(dx * dx + dy * dy + dz * dz);
        float inv = 1.0f / fmaxf(nrm, 1e-12f);
        float x = dx * inv, y = dy * inv, z = dz * inv;

        float z2     = z * z;
        float fTmp0B = -1.092548430592079f * z;
        float fC1    = x * x - y * y;
        float fS1    = 2.0f * x * y;
        float fTmp0C = -2.285228997322329f * z2 + 0.4570457994644658f;
        float fTmp1B = 1.445305721320277f * z;
        float fC2    = x * fC1 - y * fS1;
        float fS2    = x * fS1 + y * fC1;

        float sh[16];
        sh[0]  = 0.2820947917738781f;
        sh[1]  = -0.48860251190292f * y;
        sh[2]  = 0.48860251190292f * z;
        sh[3]  = -0.48860251190292f * x;
        sh[4]  = 0.5462742152960395f * fS1;
        sh[5]  = fTmp0B * y;
        sh[6]  = 0.9461746957575601f * z2 - 0.3153915652525201f;
        sh[7]  = fTmp0B * x;
        sh[8]  = 0.5462742152960395f * fC1;
        sh[9]  = -0.5900435899266435f * fS2;
        sh[10] = fTmp1B * fS1;
        sh[11] = fTmp0C * y;
        sh[12] = z * (1.865881662950577f * z2 - 1.119528997770346f);
        sh[13] = fTmp0C * x;
        sh[14] = fTmp1B * fC1;
        sh[15] = -0.5900435899266435f * fC2;

        int deg = sh_deg_p[0];
        int nb  = (deg + 1) * (deg + 1);
        #pragma unroll
        for (int i = 0; i < 16; ++i)
            XT[(32 + i) * 64 + e] = (i < nb) ? sh[i] : 0.0f;
    }
    if (tid < 128) {
        int j = tid;
        int id = embed_ids[c];
        float acc = b0[j];
        #pragma unroll
        for (int e2 = 0; e2 < 16; ++e2)
            acc += emb_tab[(size_t)id * 16 + e2] * W0[e2 * 128 + j];
        sCB[j] = acc;
        sB1[j] = b1[j];
        sW2[j * 4 + 0] = W2[j * 3 + 0];
        sW2[j * 4 + 1] = W2[j * 3 + 1];
        sW2[j * 4 + 2] = W2[j * 3 + 2];
        sW2[j * 4 + 3] = 0.0f;
    }
    if (tid < 3) sB2[tid] = b2[tid];
    __syncthreads();

    const int ex = tid & 15;   // owns elements ex*4 .. ex*4+3
    const int jx = tid >> 4;   // owns hidden j jx*8 .. jx*8+7

    // ---------------- layer 0: h0 = relu(cbias + X @ W0[16:64,:]) ----------------
    float acc0[4][8];
    {
        float cb[8];
        #pragma unroll
        for (int jj = 0; jj < 8; ++jj) cb[jj] = sCB[jx * 8 + jj];
        #pragma unroll
        for (int i = 0; i < 4; ++i)
            #pragma unroll
            for (int jj = 0; jj < 8; ++jj) acc0[i][jj] = cb[jj];
    }
    {
        const float* W0f = W0 + 16 * 128 + jx * 8;   // row k of the feats+sh part
        #pragma unroll 4
        for (int k = 0; k < 48; ++k) {
            float4 xv4 = *(const float4*)&XT[k * 64 + ex * 4];
            float4 wa  = *(const float4*)(W0f + k * 128);
            float4 wb  = *(const float4*)(W0f + k * 128 + 4);
            float xv[4] = {xv4.x, xv4.y, xv4.z, xv4.w};
            float wv[8] = {wa.x, wa.y, wa.z, wa.w, wb.x, wb.y, wb.z, wb.w};
            #pragma unroll
            for (int i = 0; i < 4; ++i)
                #pragma unroll
                for (int jj = 0; jj < 8; ++jj)
                    acc0[i][jj] += xv[i] * wv[jj];
        }
    }
    // relu + store H0^T
    #pragma unroll
    for (int jj = 0; jj < 8; ++jj) {
        float4 v;
        v.x = fmaxf(acc0[0][jj], 0.0f);
        v.y = fmaxf(acc0[1][jj], 0.0f);
        v.z = fmaxf(acc0[2][jj], 0.0f);
        v.w = fmaxf(acc0[3][jj], 0.0f);
        *(float4*)&HT[(jx * 8 + jj) * 64 + ex * 4] = v;
    }
    __syncthreads();

    // ---------------- layer 1: h1 = relu(b1 + h0 @ W1) ----------------
    float acc1[4][8];
    {
        float cb[8];
        #pragma unroll
        for (int jj = 0; jj < 8; ++jj) cb[jj] = sB1[jx * 8 + jj];
        #pragma unroll
        for (int i = 0; i < 4; ++i)
            #pragma unroll
            for (int jj = 0; jj < 8; ++jj) acc1[i][jj] = cb[jj];
    }
    {
        const float* W1p = W1 + jx * 8;
        #pragma unroll 4
        for (int k = 0; k < 128; ++k) {
            float4 hv4 = *(const float4*)&HT[k * 64 + ex * 4];
            float4 wa  = *(const float4*)(W1p + k * 128);
            float4 wb  = *(const float4*)(W1p + k * 128 + 4);
            float hv[4] = {hv4.x, hv4.y, hv4.z, hv4.w};
            float wv[8] = {wa.x, wa.y, wa.z, wa.w, wb.x, wb.y, wb.z, wb.w};
            #pragma unroll
            for (int i = 0; i < 4; ++i)
                #pragma unroll
                for (int jj = 0; jj < 8; ++jj)
                    acc1[i][jj] += hv[i] * wv[jj];
        }
    }
    __syncthreads();   // all reads of H0^T done before overwrite
    #pragma unroll
    for (int jj = 0; jj < 8; ++jj) {
        float4 v;
        v.x = fmaxf(acc1[0][jj], 0.0f);
        v.y = fmaxf(acc1[1][jj], 0.0f);
        v.z = fmaxf(acc1[2][jj], 0.0f);
        v.w = fmaxf(acc1[3][jj], 0.0f);
        *(float4*)&HT[(jx * 8 + jj) * 64 + ex * 4] = v;
    }
    __syncthreads();

    // ---------------- layer 2: out = b2 + h1 @ W2 ----------------
    if (tid < 192) {
        int e = tid / 3;
        int o = tid - e * 3;
        int n = n0 + e;
        if (n < N) {
            float a = sB2[o];
            #pragma unroll 8
            for (int k = 0; k < 128; ++k)
                a += HT[k * 64 + e] * sW2[k * 4 + o];
            // addr = ((c*N + n0)*3) + tid  -> fully coalesced
            out[((size_t)c * N + n) * 3 + o] = a;
        }
    }
}

extern "C" void kernel_launch(void* const* d_in, const int* in_sizes, int n_in,
                              void* d_out, int out_size, void* d_ws, size_t ws_size,
                              hipStream_t stream) {
    const float* feats   = (const float*)d_in[0];
    const float* dirs    = (const float*)d_in[1];
    const float* emb_tab = (const float*)d_in[2];
    const float* W0      = (const float*)d_in[3];
    const float* b0      = (const float*)d_in[4];
    const float* W1      = (const float*)d_in[5];
    const float* b1      = (const float*)d_in[6];
    const float* W2      = (const float*)d_in[7];
    const float* b2      = (const float*)d_in[8];
    const int*   eids    = (const int*)d_in[9];
    const int*   shd     = (const int*)d_in[10];
    float* outp          = (float*)d_out;

    int N = in_sizes[0] / 32;    // features [N,32]
    int C = in_sizes[9];         // embed_ids [C]

    dim3 grid((N + TM - 1) / TM, C);
    vdc_mlp_kernel<<<grid, BLOCK, 0, stream>>>(
        feats, dirs, emb_tab, W0, b0, W1, b1, W2, b2, eids, shd, outp, N);
}

// Round 2
// 299.155 us; speedup vs baseline: 2.4266x; 2.4266x over previous
//
#include <hip/hip_runtime.h>
#include <cstdint>
#include <cstddef>

typedef _Float16 half8 __attribute__((ext_vector_type(8)));
typedef float floatx16 __attribute__((ext_vector_type(16)));

// LDS arena offsets (bytes). Total 65536.
//  phase A: X [128m][64k]f16 @0 (16K), W0T [128n][64k]f16 @16384 (16K), W1T [128n][128k]f16 @32768 (32K)
//  phase B: H0 [128m][128k]f16 @0 (32K, overwrites X+W0T), W1T @32768
//  phase C: H1T [128k][132m]f16 @0 (33792B, overwrites H0 and 1K of dead W1T)
#define LDS_X    0
#define LDS_W0T  16384
#define LDS_W1T  32768
#define LDS_H0   0
#define LDS_H1T  0

__device__ __forceinline__ uint32_t pk2(float a, float b) {
    union { _Float16 h[2]; uint32_t u; } x;
    x.h[0] = (_Float16)a; x.h[1] = (_Float16)b;
    return x.u;
}

// Prep: transpose weights to f16 in workspace.
// ws f16 layout: W0T [128n][64k] (k = W0 rows 16..63; pad k 48..63 untouched),
//                W1T [128n][128k] at f16-offset 8192.
__global__ void vdc_prep_kernel(const float* __restrict__ W0,
                                const float* __restrict__ W1,
                                _Float16* __restrict__ ws) {
    int i = blockIdx.x * 256 + threadIdx.x;
    if (i < 6144) {                     // 128 * 48
        int n = i & 127, k = i >> 7;    // k in 0..47
        ws[n * 64 + k] = (_Float16)W0[(16 + k) * 128 + n];
    } else {
        int j = i - 6144;               // 128 * 128
        int n = j & 127, k = j >> 7;
        ws[8192 + n * 128 + k] = (_Float16)W1[k * 128 + n];
    }
}

__global__ __launch_bounds__(256) void vdc_mlp_kernel(
    const float* __restrict__ feats,      // [N,32]
    const float* __restrict__ dirs,       // [C,N,3]
    const float* __restrict__ emb_tab,    // [1000,16]
    const float* __restrict__ W0,         // [64,128]
    const float* __restrict__ b0,         // [128]
    const float* __restrict__ b1,         // [128]
    const float* __restrict__ W2,         // [128,3]
    const float* __restrict__ b2,         // [3]
    const int* __restrict__ embed_ids,    // [C]
    const int* __restrict__ sh_deg_p,     // [1]
    const _Float16* __restrict__ ws,      // prepped W0T/W1T
    float* __restrict__ out,              // [C,N,3]
    int N)
{
    __shared__ uint4 ldsbuf[4096];        // 64 KB
    char* lds = (char*)ldsbuf;

    const int tid  = threadIdx.x;
    const int c    = blockIdx.y;
    const int n0   = blockIdx.x * 128;
    const int lane = tid & 63;
    const int w    = tid >> 6;
    const int ln   = lane & 31;
    const int hl   = lane >> 5;          // k-half for A/B frags
    const int mp   = w & 1;              // m-pair of this wave
    const int np   = w >> 1;             // n-pair of this wave
    const int mb0  = mp * 64, mb1 = mp * 64 + 32;
    const int nb0  = np * 64, nb1 = np * 64 + 32;

    // ---- W1T global loads (held in regs; LDS-written after layer0) ----
    const uint4* w1u = (const uint4*)(ws + 8192);
    uint4 w1hold[8];
    #pragma unroll
    for (int i = 0; i < 8; ++i) w1hold[i] = w1u[i * 256 + tid];

    // ---- W0T staging: ws granules -> swizzled LDS ----
    {
        const uint4* w0u = (const uint4*)ws;
        #pragma unroll
        for (int i = 0; i < 4; ++i) {
            int idx = i * 256 + tid;
            int nn = idx >> 3, g = idx & 7;
            uint4 v = w0u[idx];
            *(uint4*)(lds + LDS_W0T + nn * 128 + ((g ^ (nn & 7)) * 16)) = v;
        }
    }

    // ---- X staging: feats rows (k 0..31) ----
    {
        int e = tid >> 1, hf = tid & 1;
        int n = n0 + e; if (n >= N) n = N - 1;
        const float4* fp = (const float4*)(feats + (size_t)n * 32 + hf * 16);
        #pragma unroll
        for (int q = 0; q < 4; ++q) {
            float4 f = fp[q];
            uint2 u; u.x = pk2(f.x, f.y); u.y = pk2(f.z, f.w);
            int kb = hf * 2 + (q >> 1);
            *(uint2*)(lds + LDS_X + e * 128 + ((kb ^ (e & 7)) * 16) + (q & 1) * 8) = u;
        }
    }

    // ---- X staging: SH basis (k 32..47) ----
    if (tid < 128) {
        int e = tid;
        int n = n0 + e; if (n >= N) n = N - 1;
        const float* dp = dirs + ((size_t)c * N + n) * 3;
        float dx = dp[0], dy = dp[1], dz = dp[2];
        float nrm = sqrtf(dx * dx + dy * dy + dz * dz);
        float inv = 1.0f / fmaxf(nrm, 1e-12f);
        float x = dx * inv, y = dy * inv, z = dz * inv;

        float z2     = z * z;
        float fTmp0B = -1.092548430592079f * z;
        float fC1    = x * x - y * y;
        float fS1    = 2.0f * x * y;
        float fTmp0C = -2.285228997322329f * z2 + 0.4570457994644658f;
        float fTmp1B = 1.445305721320277f * z;
        float fC2    = x * fC1 - y * fS1;
        float fS2    = x * fS1 + y * fC1;

        float sh[16];
        sh[0]  = 0.2820947917738781f;
        sh[1]  = -0.48860251190292f * y;
        sh[2]  = 0.48860251190292f * z;
        sh[3]  = -0.48860251190292f * x;
        sh[4]  = 0.5462742152960395f * fS1;
        sh[5]  = fTmp0B * y;
        sh[6]  = 0.9461746957575601f * z2 - 0.3153915652525201f;
        sh[7]  = fTmp0B * x;
        sh[8]  = 0.5462742152960395f * fC1;
        sh[9]  = -0.5900435899266435f * fS2;
        sh[10] = fTmp1B * fS1;
        sh[11] = fTmp0C * y;
        sh[12] = z * (1.865881662950577f * z2 - 1.119528997770346f);
        sh[13] = fTmp0C * x;
        sh[14] = fTmp1B * fC1;
        sh[15] = -0.5900435899266435f * fC2;

        int deg = sh_deg_p[0];
        int nb  = (deg + 1) * (deg + 1);
        #pragma unroll
        for (int i = 0; i < 16; ++i) if (i >= nb) sh[i] = 0.0f;

        uint4 u0, u1;
        u0.x = pk2(sh[0], sh[1]);  u0.y = pk2(sh[2], sh[3]);
        u0.z = pk2(sh[4], sh[5]);  u0.w = pk2(sh[6], sh[7]);
        u1.x = pk2(sh[8], sh[9]);  u1.y = pk2(sh[10], sh[11]);
        u1.z = pk2(sh[12], sh[13]); u1.w = pk2(sh[14], sh[15]);
        *(uint4*)(lds + LDS_X + e * 128 + ((4 ^ (e & 7)) * 16)) = u0;
        *(uint4*)(lds + LDS_X + e * 128 + ((5 ^ (e & 7)) * 16)) = u1;
    }

    // ---- per-lane camera bias: cb[j] = b0[col] + emb . W0[0:16, col] ----
    float cb[2];
    {
        int id = embed_ids[c];
        #pragma unroll
        for (int j = 0; j < 2; ++j) {
            int col = (j ? nb1 : nb0) + ln;
            float a = b0[col];
            #pragma unroll
            for (int e2 = 0; e2 < 16; ++e2)
                a += emb_tab[(size_t)id * 16 + e2] * W0[e2 * 128 + col];
            cb[j] = a;
        }
    }

    __syncthreads();

    // ---- layer 0: D0 = X[128,48] @ W0f[48,128] ----
    floatx16 acc[2][2];
    #pragma unroll
    for (int i = 0; i < 2; ++i)
        #pragma unroll
        for (int j = 0; j < 2; ++j)
            #pragma unroll
            for (int r = 0; r < 16; ++r) acc[i][j][r] = 0.0f;

    #pragma unroll
    for (int ks = 0; ks < 3; ++ks) {
        int soff = ((ks * 2 + hl) ^ (ln & 7)) * 16;
        half8 a0 = *(const half8*)(lds + LDS_X   + (mb0 + ln) * 128 + soff);
        half8 a1 = *(const half8*)(lds + LDS_X   + (mb1 + ln) * 128 + soff);
        half8 bv0 = *(const half8*)(lds + LDS_W0T + (nb0 + ln) * 128 + soff);
        half8 bv1 = *(const half8*)(lds + LDS_W0T + (nb1 + ln) * 128 + soff);
        acc[0][0] = __builtin_amdgcn_mfma_f32_32x32x16_f16(a0, bv0, acc[0][0], 0, 0, 0);
        acc[0][1] = __builtin_amdgcn_mfma_f32_32x32x16_f16(a0, bv1, acc[0][1], 0, 0, 0);
        acc[1][0] = __builtin_amdgcn_mfma_f32_32x32x16_f16(a1, bv0, acc[1][0], 0, 0, 0);
        acc[1][1] = __builtin_amdgcn_mfma_f32_32x32x16_f16(a1, bv1, acc[1][1], 0, 0, 0);
    }

    __syncthreads();   // all layer0 frag reads complete

    // ---- W1T LDS writes (loads have been in flight since kernel start) ----
    #pragma unroll
    for (int i = 0; i < 8; ++i) {
        int idx = i * 256 + tid;
        int nn = idx >> 4, g = idx & 15;
        *(uint4*)(lds + LDS_W1T + nn * 256 + ((g ^ (nn & 7)) * 16)) = w1hold[i];
    }

    // ---- layer0 epilogue: +cbias, relu, f16, transpose-write H0[m][k] ----
    #pragma unroll
    for (int i = 0; i < 2; ++i) {
        int mbase = (i ? mb1 : mb0) + 4 * hl;
        #pragma unroll
        for (int j = 0; j < 2; ++j) {
            int k1  = (j ? nb1 : nb0) + ln;   // layer1 k-index
            int kb1 = k1 >> 3;
            int klow = (k1 & 7) * 2;
            #pragma unroll
            for (int r = 0; r < 16; ++r) {
                int s = r & 3, rq = r >> 2;
                int m = mbase + rq * 8 + s;
                float v = fmaxf(acc[i][j][r] + cb[j], 0.0f);
                *(_Float16*)(lds + LDS_H0 + m * 256 +
                             ((kb1 ^ (s + 4 * hl)) * 16) + klow) = (_Float16)v;
            }
        }
    }

    float bb[2] = { b1[nb0 + ln], b1[nb1 + ln] };

    __syncthreads();

    // ---- layer 1: D1 = H0[128,128] @ W1[128,128] ----
    floatx16 acc2[2][2];
    #pragma unroll
    for (int i = 0; i < 2; ++i)
        #pragma unroll
        for (int j = 0; j < 2; ++j)
            #pragma unroll
            for (int r = 0; r < 16; ++r) acc2[i][j][r] = 0.0f;

    #pragma unroll
    for (int ks = 0; ks < 8; ++ks) {
        int soff = ((ks * 2 + hl) ^ (ln & 7)) * 16;
        half8 a0 = *(const half8*)(lds + LDS_H0  + (mb0 + ln) * 256 + soff);
        half8 a1 = *(const half8*)(lds + LDS_H0  + (mb1 + ln) * 256 + soff);
        half8 bv0 = *(const half8*)(lds + LDS_W1T + (nb0 + ln) * 256 + soff);
        half8 bv1 = *(const half8*)(lds + LDS_W1T + (nb1 + ln) * 256 + soff);
        acc2[0][0] = __builtin_amdgcn_mfma_f32_32x32x16_f16(a0, bv0, acc2[0][0], 0, 0, 0);
        acc2[0][1] = __builtin_amdgcn_mfma_f32_32x32x16_f16(a0, bv1, acc2[0][1], 0, 0, 0);
        acc2[1][0] = __builtin_amdgcn_mfma_f32_32x32x16_f16(a1, bv0, acc2[1][0], 0, 0, 0);
        acc2[1][1] = __builtin_amdgcn_mfma_f32_32x32x16_f16(a1, bv1, acc2[1][1], 0, 0, 0);
    }

    __syncthreads();   // all layer1 frag reads complete

    // ---- layer1 epilogue: +b1, relu, f16, packed b64 writes to H1T[k][132m] ----
    #pragma unroll
    for (int i = 0; i < 2; ++i) {
        #pragma unroll
        for (int j = 0; j < 2; ++j) {
            int k1 = (j ? nb1 : nb0) + ln;
            #pragma unroll
            for (int rq = 0; rq < 4; ++rq) {
                int m0 = (i ? mb1 : mb0) + rq * 8 + 4 * hl;
                float v0 = fmaxf(acc2[i][j][rq * 4 + 0] + bb[j], 0.0f);
                float v1 = fmaxf(acc2[i][j][rq * 4 + 1] + bb[j], 0.0f);
                float v2 = fmaxf(acc2[i][j][rq * 4 + 2] + bb[j], 0.0f);
                float v3 = fmaxf(acc2[i][j][rq * 4 + 3] + bb[j], 0.0f);
                uint2 u; u.x = pk2(v0, v1); u.y = pk2(v2, v3);
                *(uint2*)(lds + LDS_H1T + k1 * 264 + m0 * 2) = u;
            }
        }
    }

    __syncthreads();

    // ---- layer 2: out = b2 + H1 @ W2  (VALU; 1.5% of FLOPs) ----
    #pragma unroll
    for (int p = 0; p < 2; ++p) {
        int idx = p * 256 + tid;
        int e = idx & 127, o = idx >> 7;   // o uniform per wave
        int n = n0 + e;
        if (o < 3 && n < N) {
            float a = b2[o];
            const char* hp = lds + LDS_H1T + e * 2;
            #pragma unroll 8
            for (int k = 0; k < 128; ++k)
                a += (float)(*(const _Float16*)(hp + k * 264)) * W2[k * 3 + o];
            out[((size_t)c * N + n) * 3 + o] = a;
        }
    }
}

extern "C" void kernel_launch(void* const* d_in, const int* in_sizes, int n_in,
                              void* d_out, int out_size, void* d_ws, size_t ws_size,
                              hipStream_t stream) {
    const float* feats   = (const float*)d_in[0];
    const float* dirs    = (const float*)d_in[1];
    const float* emb_tab = (const float*)d_in[2];
    const float* W0      = (const float*)d_in[3];
    const float* b0      = (const float*)d_in[4];
    const float* W1      = (const float*)d_in[5];
    const float* b1      = (const float*)d_in[6];
    const float* W2      = (const float*)d_in[7];
    const float* b2      = (const float*)d_in[8];
    const int*   eids    = (const int*)d_in[9];
    const int*   shd     = (const int*)d_in[10];
    float* outp          = (float*)d_out;

    int N = in_sizes[0] / 32;    // features [N,32]
    int C = in_sizes[9];         // embed_ids [C]

    _Float16* wsh = (_Float16*)d_ws;   // 48 KB used

    vdc_prep_kernel<<<88, 256, 0, stream>>>(W0, W1, wsh);

    dim3 grid((N + 127) / 128, C);
    vdc_mlp_kernel<<<grid, 256, 0, stream>>>(
        feats, dirs, emb_tab, W0, b0, b1, W2, b2, eids, shd, wsh, outp, N);
}